// Round 1
// baseline (4542.982 us; speedup 1.0000x reference)
//
#include <hip/hip_runtime.h>
#include <hip/hip_bf16.h>
#include <stdint.h>

typedef __attribute__((ext_vector_type(4))) float f32x4;
typedef __attribute__((ext_vector_type(8))) short short8;
typedef __attribute__((ext_vector_type(4))) short short4v;

// ---------------- workspace layout (bytes) ----------------
#define OFF_XBF  ((size_t)0)            // [8192][1024] bf16 = 16777216
#define OFF_WIT  ((size_t)16777216)     // [2*4096][1024] bf16 = 16777216
#define OFF_WHT  ((size_t)33554432)     // [2*4096][1024] bf16 = 16777216
#define OFF_XG   ((size_t)50331648)     // [8192][8192] bf16 = 134217728
#define OFF_H    ((size_t)184549376)    // [2 parity][2 dir][32][1024] bf16 = 262144
#define OFF_BIAS ((size_t)184811520)    // [8192] f32 = 32768
#define OFF_LEN  ((size_t)184844288)    // [32] i32
#define OFF_CNT  ((size_t)184844416)    // 2 x 128B counters

__device__ __forceinline__ short f2bf(float f) {
  union { float f; uint32_t u; } v; v.f = f;
  uint32_t u = v.u;
  uint32_t r = (u + 0x7fffu + ((u >> 16) & 1u)) >> 16;
  return (short)r;
}
__device__ __forceinline__ float bf2f(short s) {
  union { uint32_t u; float f; } v; v.u = ((uint32_t)(uint16_t)s) << 16;
  return v.f;
}

// ---------------- lengths ----------------
__global__ void k_len(const int* __restrict__ mask, int* __restrict__ len) {
  int b = threadIdx.x;
  if (b < 32) {
    int s = 0;
    for (int t = 0; t < 256; t++) s += mask[b * 256 + t];
    len[b] = s;
  }
}

// ---------------- x -> bf16, [B,T,D] -> [(t*32+b), D] ----------------
__global__ void k_xconv(const float* __restrict__ x, short* __restrict__ xbf) {
  int bid = blockIdx.x;              // 0..8191 = b*256 + t
  int b = bid >> 8, t = bid & 255;
  int d = threadIdx.x * 4;
  const float* sp = x + ((size_t)bid) * 1024 + d;
  float4 v = *(const float4*)sp;
  short4v o;
  o.x = f2bf(v.x); o.y = f2bf(v.y); o.z = f2bf(v.z); o.w = f2bf(v.w);
  *(short4v*)(xbf + ((size_t)(t * 32 + b)) * 1024 + d) = o;
}

// ------- weights: transpose [k][4096] f32 -> [n_perm][k] bf16, gate-interleaved perm -------
// perm: p = g4*16 + gate*4 + h4  <->  orig col c = gate*1024 + g4*4 + h4
__global__ void k_wprep(const float* __restrict__ Wi_f, const float* __restrict__ Wi_b,
                        const float* __restrict__ Wh_f, const float* __restrict__ Wh_b,
                        short* __restrict__ WiT, short* __restrict__ WhT) {
  __shared__ short ldsT[64 * 72];
  int id = blockIdx.x;               // 4096 blocks
  int which = id >> 11, dir = (id >> 10) & 1, tile = id & 1023;
  int kt = (tile >> 6) * 64, c0 = (tile & 63) * 64;
  const float* src = (which == 0) ? (dir == 0 ? Wi_f : Wi_b)
                                  : (dir == 0 ? Wh_f : Wh_b);
  short* dst = (which == 0) ? WiT : WhT;
  int tid = threadIdx.x;
#pragma unroll 4
  for (int i = 0; i < 16; i++) {
    int idx = i * 256 + tid;
    int kk = idx >> 6, cc = idx & 63;
    float v = src[(size_t)(kt + kk) * 4096 + c0 + cc];
    ldsT[cc * 72 + kk] = f2bf(v);    // transposed store
  }
  __syncthreads();
  int rowc = tid >> 2, part = tid & 3;
  int cg = c0 + rowc;
  int gate = cg >> 10, hc = cg & 1023;
  int p = (hc >> 2) * 16 + gate * 4 + (hc & 3);
  int n = dir * 4096 + p;
  short8 v0 = *(short8*)&ldsT[rowc * 72 + part * 16];
  short8 v1 = *(short8*)&ldsT[rowc * 72 + part * 16 + 8];
  *(short8*)(dst + (size_t)n * 1024 + kt + part * 16) = v0;
  *(short8*)(dst + (size_t)n * 1024 + kt + part * 16 + 8) = v1;
}

// ---------------- bias permute ----------------
__global__ void k_bias(const float* __restrict__ bf_, const float* __restrict__ bb_,
                       float* __restrict__ bp) {
  int n = blockIdx.x * 256 + threadIdx.x;   // 0..8191
  int dir = n >> 12, p = n & 4095;
  int gate = (p >> 2) & 3, g4 = p >> 4, h4 = p & 3;
  int c = gate * 1024 + g4 * 4 + h4;
  bp[n] = (dir == 0 ? bf_ : bb_)[c];
}

// ---------------- XG = xbf @ WiT^T + bias : [8192][8192] bf16 ----------------
__global__ void k_gemm(const short* __restrict__ Abf,   // xbf [8192][1024]
                       const short* __restrict__ Bbf,   // WiT [8192][1024]
                       const float* __restrict__ bias,  // [8192]
                       short* __restrict__ C) {         // XG [8192][8192]
  __shared__ char Ash[128 * 144];
  __shared__ char Bsh[128 * 144];
  const int tid = threadIdx.x;
  const int lane = tid & 63, wid = tid >> 6;
  const int wm = wid >> 1, wn = wid & 1;
  const int l15 = lane & 15, lg = lane >> 4;
  const int m0 = blockIdx.y * 128, n0 = blockIdx.x * 128;

  f32x4 acc[4][4];
#pragma unroll
  for (int i = 0; i < 4; i++)
#pragma unroll
    for (int j = 0; j < 4; j++) acc[i][j] = (f32x4){0.f, 0.f, 0.f, 0.f};

  for (int kt = 0; kt < 1024; kt += 64) {
#pragma unroll
    for (int i = 0; i < 4; i++) {
      int chunk = i * 256 + tid;          // 0..1023
      int row = chunk >> 3, kc = chunk & 7;
      *(short8*)(Ash + row * 144 + kc * 16) =
          *(const short8*)(Abf + (size_t)(m0 + row) * 1024 + kt + kc * 8);
      *(short8*)(Bsh + row * 144 + kc * 16) =
          *(const short8*)(Bbf + (size_t)(n0 + row) * 1024 + kt + kc * 8);
    }
    __syncthreads();
#pragma unroll
    for (int kk = 0; kk < 2; kk++) {
      short8 af[4], bfv[4];
#pragma unroll
      for (int mt = 0; mt < 4; mt++)
        af[mt] = *(const short8*)(Ash + (wm * 64 + mt * 16 + l15) * 144 + kk * 64 + lg * 16);
#pragma unroll
      for (int ntc = 0; ntc < 4; ntc++)
        bfv[ntc] = *(const short8*)(Bsh + (wn * 64 + ntc * 16 + l15) * 144 + kk * 64 + lg * 16);
#pragma unroll
      for (int mt = 0; mt < 4; mt++)
#pragma unroll
        for (int ntc = 0; ntc < 4; ntc++)
          acc[mt][ntc] = __builtin_amdgcn_mfma_f32_16x16x32_bf16(af[mt], bfv[ntc], acc[mt][ntc], 0, 0, 0);
    }
    __syncthreads();
  }
  float bs[4];
#pragma unroll
  for (int ntc = 0; ntc < 4; ntc++) bs[ntc] = bias[n0 + wn * 64 + ntc * 16 + l15];
#pragma unroll
  for (int mt = 0; mt < 4; mt++) {
    int row = m0 + wm * 64 + mt * 16 + lg * 4;
#pragma unroll
    for (int ntc = 0; ntc < 4; ntc++) {
      int col = n0 + wn * 64 + ntc * 16 + l15;
#pragma unroll
      for (int r = 0; r < 4; r++)
        C[(size_t)(row + r) * 8192 + col] = f2bf(acc[mt][ntc][r] + bs[ntc]);
    }
  }
}

// ---------------- persistent recurrence ----------------
// 256 blocks x 256 thr. dir = bid>>7, rblk = bid&127 owns h-cols [rblk*8, rblk*8+8)
// = permuted z-cols [rblk*32, rblk*32+32). Wave (mt,nt): 16 batches x 16 cols.
// Wh B-fragments live in 128 VGPRs for the whole kernel.
__global__ void __launch_bounds__(256, 1) k_recur(
    const short* __restrict__ XG,    // [8192][8192] bf16
    const short* __restrict__ WhT,   // [2*4096][1024] bf16
    const int* __restrict__ len,
    short* __restrict__ hbuf,        // [2][2][32][1024] bf16
    float* __restrict__ out,         // [32][256][2048] f32
    unsigned int* __restrict__ cnt) {
  __shared__ char Hld[65536];
  const int tid = threadIdx.x;
  const int lane = tid & 63;
  const int wid = tid >> 6;
  const int bidx = blockIdx.x;
  const int dir = bidx >> 7;
  const int rblk = bidx & 127;
  const int mt = wid >> 1, nt = wid & 1;
  const int l15 = lane & 15, lg = lane >> 4;

  // B-fragments (Wh columns), resident in registers
  const int ncol = dir * 4096 + rblk * 32 + nt * 16 + l15;
  const short* wrow = WhT + (size_t)ncol * 1024;
  short8 bfr[32];
#pragma unroll
  for (int kk = 0; kk < 32; kk++)
    bfr[kk] = *(const short8*)(wrow + kk * 32 + lg * 8);

  float c_reg[4] = {0.f, 0.f, 0.f, 0.f};
  int lenv[4];
#pragma unroll
  for (int r = 0; r < 4; r++) lenv[r] = len[mt * 16 + lg * 4 + r];

  unsigned int* mycnt = cnt + dir * 32;    // 128B apart
  const int c4 = l15;
  const int gate = c4 >> 2;
  const int colg = dir * 4096 + rblk * 32 + nt * 16 + c4;
  const int brow = mt * 16 + l15;
  const int sw = (brow & 7) << 4;
  const int abase = brow * 2048 + (lg << 4);

  for (int t = 0; t < 256; t++) {
    // stage h (read parity t&1) into LDS with XOR swizzle
    const short* hsrc = hbuf + (size_t)(((t & 1) * 2 + dir) * 32768);
#pragma unroll 4
    for (int i = 0; i < 16; i++) {
      int chunk = i * 256 + tid;       // 0..4095, 16B each
      int row = chunk >> 7;
      short8 v = *(const short8*)(hsrc + chunk * 8);
      int dst = (chunk * 16) ^ ((row & 7) << 4);
      *(short8*)(Hld + dst) = v;
    }
    __syncthreads();

    f32x4 acc = (f32x4){0.f, 0.f, 0.f, 0.f};
#pragma unroll
    for (int kk = 0; kk < 32; kk++) {
      short8 af = *(const short8*)(Hld + ((abase + kk * 64) ^ sw));
      acc = __builtin_amdgcn_mfma_f32_16x16x32_bf16(af, bfr[kk], acc, 0, 0, 0);
    }

#pragma unroll
    for (int r = 0; r < 4; r++) {
      int b_r = mt * 16 + lg * 4 + r;
      int tt = (dir == 0) ? t : ((lenv[r] - 1 - t) & 255);
      float xg = bf2f(XG[(size_t)(tt * 32 + b_r) * 8192 + colg]);
      float z = acc[r] + xg;
      float s = (gate == 2) ? tanhf(z) : 1.f / (1.f + expf(-z));
      float x8 = __shfl_xor(s, 8);     // i<->g, f<->o
      float pI = s * x8;               // on i-lanes: sig(i)*tanh(g)
      float v = (gate == 0) ? pI : s;
      float x4 = __shfl_xor(v, 4);     // i-lane receives sig(f)
      float o4 = __shfl_xor(x8, 4);    // i-lane receives sig(o)
      if (c4 < 4) {
        float cn = fmaf(x4, c_reg[r], pI);
        c_reg[r] = cn;
        float h = o4 * tanhf(cn);
        int hcol = rblk * 8 + nt * 4 + c4;
        hbuf[(size_t)((((t + 1) & 1) * 2 + dir) * 32768) + b_r * 1024 + hcol] = f2bf(h);
        out[((size_t)b_r * 256 + tt) * 2048 + dir * 1024 + hcol] = h;
      }
    }

    // grid barrier (per direction), monotonic counter
    __syncthreads();
    if (tid == 0) {
      __hip_atomic_fetch_add(mycnt, 1u, __ATOMIC_ACQ_REL, __HIP_MEMORY_SCOPE_AGENT);
      unsigned int tgt = (unsigned int)(t + 1) * 128u;
      while (__hip_atomic_load(mycnt, __ATOMIC_ACQUIRE, __HIP_MEMORY_SCOPE_AGENT) < tgt)
        __builtin_amdgcn_s_sleep(1);
    }
    __syncthreads();
  }
}

extern "C" void kernel_launch(void* const* d_in, const int* in_sizes, int n_in,
                              void* d_out, int out_size, void* d_ws, size_t ws_size,
                              hipStream_t stream) {
  const float* x    = (const float*)d_in[0];
  const int*   mask = (const int*)d_in[1];
  const float* Wi_f = (const float*)d_in[2];
  const float* Wh_f = (const float*)d_in[3];
  const float* b_f  = (const float*)d_in[4];
  const float* Wi_b = (const float*)d_in[5];
  const float* Wh_b = (const float*)d_in[6];
  const float* b_b  = (const float*)d_in[7];
  float* out = (float*)d_out;
  char* ws = (char*)d_ws;

  short* xbf  = (short*)(ws + OFF_XBF);
  short* WiT  = (short*)(ws + OFF_WIT);
  short* WhT  = (short*)(ws + OFF_WHT);
  short* XG   = (short*)(ws + OFF_XG);
  short* hbuf = (short*)(ws + OFF_H);
  float* bp   = (float*)(ws + OFF_BIAS);
  int*   len  = (int*)(ws + OFF_LEN);
  unsigned int* cnt = (unsigned int*)(ws + OFF_CNT);

  hipMemsetAsync(hbuf, 0, 262144, stream);
  hipMemsetAsync(cnt, 0, 256, stream);

  k_len<<<1, 64, 0, stream>>>(mask, len);
  k_xconv<<<8192, 256, 0, stream>>>(x, xbf);
  k_wprep<<<4096, 256, 0, stream>>>(Wi_f, Wi_b, Wh_f, Wh_b, WiT, WhT);
  k_bias<<<32, 256, 0, stream>>>(b_f, b_b, bp);

  dim3 g(64, 64);
  k_gemm<<<g, 256, 0, stream>>>(xbf, WiT, bp, XG);

  k_recur<<<256, 256, 0, stream>>>(XG, WhT, len, hbuf, out, cnt);
}

// Round 3
// 1804.460 us; speedup vs baseline: 2.5176x; 2.5176x over previous
//
#include <hip/hip_runtime.h>
#include <hip/hip_bf16.h>
#include <stdint.h>

typedef __attribute__((ext_vector_type(4))) float f32x4;
typedef __attribute__((ext_vector_type(8))) short short8;
typedef __attribute__((ext_vector_type(4))) short short4v;

// ---------------- workspace layout (bytes) ----------------
#define OFF_XBF  ((size_t)0)            // [8192][1024] bf16 = 16777216
#define OFF_WIT  ((size_t)16777216)     // [2*4096][1024] bf16 = 16777216
#define OFF_WHT  ((size_t)33554432)     // [2*4096][1024] bf16 = 16777216
#define OFF_XG   ((size_t)50331648)     // [8192][8192] bf16 = 134217728
#define OFF_H    ((size_t)184549376)    // [2 parity][2 dir][32][1024] bf16 = 262144
#define OFF_BIAS ((size_t)184811520)    // [8192] f32 = 32768
#define OFF_LEN  ((size_t)184844288)    // [32] i32
#define OFF_CNT  ((size_t)184844416)    // 2 x 128B counters

__device__ __forceinline__ short f2bf(float f) {
  union { float f; uint32_t u; } v; v.f = f;
  uint32_t u = v.u;
  uint32_t r = (u + 0x7fffu + ((u >> 16) & 1u)) >> 16;
  return (short)r;
}
__device__ __forceinline__ float bf2f(short s) {
  union { uint32_t u; float f; } v; v.u = ((uint32_t)(uint16_t)s) << 16;
  return v.f;
}

// ---------------- lengths ----------------
__global__ void k_len(const int* __restrict__ mask, int* __restrict__ len) {
  int b = threadIdx.x;
  if (b < 32) {
    int s = 0;
    for (int t = 0; t < 256; t++) s += mask[b * 256 + t];
    len[b] = s;
  }
}

// ---------------- x -> bf16, [B,T,D] -> [(t*32+b), D] ----------------
__global__ void k_xconv(const float* __restrict__ x, short* __restrict__ xbf) {
  int bid = blockIdx.x;              // 0..8191 = b*256 + t
  int b = bid >> 8, t = bid & 255;
  int d = threadIdx.x * 4;
  const float* sp = x + ((size_t)bid) * 1024 + d;
  float4 v = *(const float4*)sp;
  short4v o;
  o.x = f2bf(v.x); o.y = f2bf(v.y); o.z = f2bf(v.z); o.w = f2bf(v.w);
  *(short4v*)(xbf + ((size_t)(t * 32 + b)) * 1024 + d) = o;
}

// ------- weights: transpose [k][4096] f32 -> [n_perm][k] bf16, gate-interleaved perm -------
// perm: p = g4*16 + gate*4 + h4  <->  orig col c = gate*1024 + g4*4 + h4
__global__ void k_wprep(const float* __restrict__ Wi_f, const float* __restrict__ Wi_b,
                        const float* __restrict__ Wh_f, const float* __restrict__ Wh_b,
                        short* __restrict__ WiT, short* __restrict__ WhT) {
  __shared__ short ldsT[64 * 72];
  int id = blockIdx.x;               // 4096 blocks
  int which = id >> 11, dir = (id >> 10) & 1, tile = id & 1023;
  int kt = (tile >> 6) * 64, c0 = (tile & 63) * 64;
  const float* src = (which == 0) ? (dir == 0 ? Wi_f : Wi_b)
                                  : (dir == 0 ? Wh_f : Wh_b);
  short* dst = (which == 0) ? WiT : WhT;
  int tid = threadIdx.x;
#pragma unroll 4
  for (int i = 0; i < 16; i++) {
    int idx = i * 256 + tid;
    int kk = idx >> 6, cc = idx & 63;
    float v = src[(size_t)(kt + kk) * 4096 + c0 + cc];
    ldsT[cc * 72 + kk] = f2bf(v);    // transposed store
  }
  __syncthreads();
  int rowc = tid >> 2, part = tid & 3;
  int cg = c0 + rowc;
  int gate = cg >> 10, hc = cg & 1023;
  int p = (hc >> 2) * 16 + gate * 4 + (hc & 3);
  int n = dir * 4096 + p;
  short8 v0 = *(short8*)&ldsT[rowc * 72 + part * 16];
  short8 v1 = *(short8*)&ldsT[rowc * 72 + part * 16 + 8];
  *(short8*)(dst + (size_t)n * 1024 + kt + part * 16) = v0;
  *(short8*)(dst + (size_t)n * 1024 + kt + part * 16 + 8) = v1;
}

// ---------------- bias permute ----------------
__global__ void k_bias(const float* __restrict__ bf_, const float* __restrict__ bb_,
                       float* __restrict__ bp) {
  int n = blockIdx.x * 256 + threadIdx.x;   // 0..8191
  int dir = n >> 12, p = n & 4095;
  int gate = (p >> 2) & 3, g4 = p >> 4, h4 = p & 3;
  int c = gate * 1024 + g4 * 4 + h4;
  bp[n] = (dir == 0 ? bf_ : bb_)[c];
}

// ---------------- XG = xbf @ WiT^T + bias : [8192][8192] bf16 ----------------
__global__ void k_gemm(const short* __restrict__ Abf,   // xbf [8192][1024]
                       const short* __restrict__ Bbf,   // WiT [8192][1024]
                       const float* __restrict__ bias,  // [8192]
                       short* __restrict__ C) {         // XG [8192][8192]
  __shared__ char Ash[128 * 144];
  __shared__ char Bsh[128 * 144];
  const int tid = threadIdx.x;
  const int lane = tid & 63, wid = tid >> 6;
  const int wm = wid >> 1, wn = wid & 1;
  const int l15 = lane & 15, lg = lane >> 4;
  const int m0 = blockIdx.y * 128, n0 = blockIdx.x * 128;

  f32x4 acc[4][4];
#pragma unroll
  for (int i = 0; i < 4; i++)
#pragma unroll
    for (int j = 0; j < 4; j++) acc[i][j] = (f32x4){0.f, 0.f, 0.f, 0.f};

  for (int kt = 0; kt < 1024; kt += 64) {
#pragma unroll
    for (int i = 0; i < 4; i++) {
      int chunk = i * 256 + tid;          // 0..1023
      int row = chunk >> 3, kc = chunk & 7;
      *(short8*)(Ash + row * 144 + kc * 16) =
          *(const short8*)(Abf + (size_t)(m0 + row) * 1024 + kt + kc * 8);
      *(short8*)(Bsh + row * 144 + kc * 16) =
          *(const short8*)(Bbf + (size_t)(n0 + row) * 1024 + kt + kc * 8);
    }
    __syncthreads();
#pragma unroll
    for (int kk = 0; kk < 2; kk++) {
      short8 af[4], bfv[4];
#pragma unroll
      for (int mt = 0; mt < 4; mt++)
        af[mt] = *(const short8*)(Ash + (wm * 64 + mt * 16 + l15) * 144 + kk * 64 + lg * 16);
#pragma unroll
      for (int ntc = 0; ntc < 4; ntc++)
        bfv[ntc] = *(const short8*)(Bsh + (wn * 64 + ntc * 16 + l15) * 144 + kk * 64 + lg * 16);
#pragma unroll
      for (int mt = 0; mt < 4; mt++)
#pragma unroll
        for (int ntc = 0; ntc < 4; ntc++)
          acc[mt][ntc] = __builtin_amdgcn_mfma_f32_16x16x32_bf16(af[mt], bfv[ntc], acc[mt][ntc], 0, 0, 0);
    }
    __syncthreads();
  }
  float bs[4];
#pragma unroll
  for (int ntc = 0; ntc < 4; ntc++) bs[ntc] = bias[n0 + wn * 64 + ntc * 16 + l15];
#pragma unroll
  for (int mt = 0; mt < 4; mt++) {
    int row = m0 + wm * 64 + mt * 16 + lg * 4;
#pragma unroll
    for (int ntc = 0; ntc < 4; ntc++) {
      int col = n0 + wn * 64 + ntc * 16 + l15;
#pragma unroll
      for (int r = 0; r < 4; r++)
        C[(size_t)(row + r) * 8192 + col] = f2bf(acc[mt][ntc][r] + bs[ntc]);
    }
  }
}

// ---------------- persistent recurrence ----------------
// 128 blocks x 512 thr (8 waves). dir = bid>>6, nblk = bid&63 owns permuted
// z-cols [nblk*64, nblk*64+64) = h-cols [nblk*16, nblk*16+16).
// Wave (mt=wid>>2, nt=wid&3): 16 batches x 16 z-cols. Wh in 128 VGPRs/wave.
// Barrier: relaxed spin + one acquire fence; h published via 8B relaxed
// agent-scope atomic stores (performed at coherence point -> no wbl2 needed).
__global__ void __launch_bounds__(512, 1) k_recur(
    const short* __restrict__ XG,    // [8192][8192] bf16
    const short* __restrict__ WhT,   // [2*4096][1024] bf16
    const int* __restrict__ len,
    short* __restrict__ hbuf,        // [2][2][32][1024] bf16
    float* __restrict__ out,         // [32][256][2048] f32
    unsigned int* __restrict__ cnt) {
  __shared__ char Hld[65536];
  const int tid = threadIdx.x;
  const int lane = tid & 63;
  const int wid = tid >> 6;
  const int bidx = blockIdx.x;
  const int dir = bidx >> 6;
  const int nblk = bidx & 63;
  const int mt = wid >> 2, nt = wid & 3;
  const int l15 = lane & 15, lg = lane >> 4;

  // B-fragments (Wh columns), resident in registers for all 256 steps
  const int ncol = dir * 4096 + nblk * 64 + nt * 16 + l15;
  const short* wrow = WhT + (size_t)ncol * 1024;
  short8 bfr[32];
#pragma unroll
  for (int kk = 0; kk < 32; kk++)
    bfr[kk] = *(const short8*)(wrow + kk * 32 + lg * 8);

  float c_reg[4] = {0.f, 0.f, 0.f, 0.f};
  int lenv[4];
#pragma unroll
  for (int r = 0; r < 4; r++) lenv[r] = len[mt * 16 + lg * 4 + r];

  unsigned int* mycnt = cnt + dir * 32;    // 128B apart
  const int c4 = l15;
  const int gate = c4 >> 2;
  const int brow = mt * 16 + l15;
  const int sw = (brow & 7) << 4;
  const int abase = brow * 2048 + (lg << 4);
  const int hcol0 = nblk * 16 + nt * 4;    // first h-col of this wave's tile

  // prefetch XG for t=0
  float xg_pf[4];
#pragma unroll
  for (int r = 0; r < 4; r++) {
    int b_r = mt * 16 + lg * 4 + r;
    int tt = (dir == 0) ? 0 : ((lenv[r] - 1) & 255);
    xg_pf[r] = bf2f(XG[(size_t)(tt * 32 + b_r) * 8192 + ncol]);
  }

  for (int t = 0; t < 256; t++) {
    // stage h (read parity t&1) into LDS with XOR swizzle (normal cached loads)
    const short* hsrc = hbuf + (size_t)(((t & 1) * 2 + dir) * 32768);
#pragma unroll
    for (int i = 0; i < 8; i++) {
      int chunk = i * 512 + tid;       // 0..4095, 16B each
      int row = chunk >> 7;
      short8 v = *(const short8*)(hsrc + chunk * 8);
      int dst = (chunk * 16) ^ ((row & 7) << 4);
      *(short8*)(Hld + dst) = v;
    }
    __syncthreads();

    // two independent MFMA chains to halve dependent latency
    f32x4 accA = (f32x4){0.f, 0.f, 0.f, 0.f};
    f32x4 accB = (f32x4){0.f, 0.f, 0.f, 0.f};
#pragma unroll
    for (int kk = 0; kk < 16; kk++) {
      short8 afA = *(const short8*)(Hld + ((abase + kk * 64) ^ sw));
      short8 afB = *(const short8*)(Hld + ((abase + (kk + 16) * 64) ^ sw));
      accA = __builtin_amdgcn_mfma_f32_16x16x32_bf16(afA, bfr[kk], accA, 0, 0, 0);
      accB = __builtin_amdgcn_mfma_f32_16x16x32_bf16(afB, bfr[kk + 16], accB, 0, 0, 0);
    }

#pragma unroll
    for (int r = 0; r < 4; r++) {
      int b_r = mt * 16 + lg * 4 + r;
      int tt = (dir == 0) ? t : ((lenv[r] - 1 - t) & 255);
      float z = accA[r] + accB[r] + xg_pf[r];
      float s = (gate == 2) ? tanhf(z) : 1.f / (1.f + expf(-z));
      float x8 = __shfl_xor(s, 8);     // i<->g, f<->o
      float pI = s * x8;               // on i-lanes: sig(i)*tanh(g)
      float v = (gate == 0) ? pI : s;
      float x4 = __shfl_xor(v, 4);     // i-lane receives sig(f)
      float o4 = __shfl_xor(x8, 4);    // i-lane receives sig(o)
      if (c4 < 4) {
        float cn = fmaf(x4, c_reg[r], pI);
        c_reg[r] = cn;
        float h = o4 * tanhf(cn);
        // pack 4 cols (lanes c4=0..3) into 8B, publish via relaxed agent atomic
        uint32_t hb = (uint32_t)(uint16_t)f2bf(h);
        uint32_t p0 = hb | (__shfl_xor(hb, 1) << 16);
        uint32_t q  = __shfl_xor(p0, 2);
        if (c4 == 0) {
          unsigned long long p = (unsigned long long)p0 | ((unsigned long long)q << 32);
          unsigned long long* haddr = (unsigned long long*)
            (hbuf + (size_t)((((t + 1) & 1) * 2 + dir) * 32768) + b_r * 1024 + hcol0);
          __hip_atomic_store(haddr, p, __ATOMIC_RELAXED, __HIP_MEMORY_SCOPE_AGENT);
        }
        out[((size_t)b_r * 256 + tt) * 2048 + dir * 1024 + hcol0 + c4] = h;
      }
    }

    // prefetch XG for t+1 (independent of barrier; keep-alive pins issue+complete here)
    int tn = (t < 255) ? t + 1 : 255;
#pragma unroll
    for (int r = 0; r < 4; r++) {
      int b_r = mt * 16 + lg * 4 + r;
      int tt = (dir == 0) ? tn : ((lenv[r] - 1 - tn) & 255);
      xg_pf[r] = bf2f(XG[(size_t)(tt * 32 + b_r) * 8192 + ncol]);
    }
    asm volatile("" : "+v"(xg_pf[0]), "+v"(xg_pf[1]), "+v"(xg_pf[2]), "+v"(xg_pf[3]));

    // grid barrier (per direction): relaxed add + relaxed spin + one acquire fence
    __syncthreads();   // compiler drains vmcnt before s_barrier -> h stores done
    if (tid == 0) {
      asm volatile("s_waitcnt vmcnt(0) lgkmcnt(0)" ::: "memory");
      __hip_atomic_fetch_add(mycnt, 1u, __ATOMIC_RELAXED, __HIP_MEMORY_SCOPE_AGENT);
      unsigned int tgt = (unsigned int)(t + 1) * 64u;
      while (__hip_atomic_load(mycnt, __ATOMIC_RELAXED, __HIP_MEMORY_SCOPE_AGENT) < tgt)
        __builtin_amdgcn_s_sleep(2);
      __builtin_amdgcn_fence(__ATOMIC_ACQUIRE, "agent");  // one buffer_inv
    }
    __syncthreads();
  }
}

extern "C" void kernel_launch(void* const* d_in, const int* in_sizes, int n_in,
                              void* d_out, int out_size, void* d_ws, size_t ws_size,
                              hipStream_t stream) {
  const float* x    = (const float*)d_in[0];
  const int*   mask = (const int*)d_in[1];
  const float* Wi_f = (const float*)d_in[2];
  const float* Wh_f = (const float*)d_in[3];
  const float* b_f  = (const float*)d_in[4];
  const float* Wi_b = (const float*)d_in[5];
  const float* Wh_b = (const float*)d_in[6];
  const float* b_b  = (const float*)d_in[7];
  float* out = (float*)d_out;
  char* ws = (char*)d_ws;

  short* xbf  = (short*)(ws + OFF_XBF);
  short* WiT  = (short*)(ws + OFF_WIT);
  short* WhT  = (short*)(ws + OFF_WHT);
  short* XG   = (short*)(ws + OFF_XG);
  short* hbuf = (short*)(ws + OFF_H);
  float* bp   = (float*)(ws + OFF_BIAS);
  int*   len  = (int*)(ws + OFF_LEN);
  unsigned int* cnt = (unsigned int*)(ws + OFF_CNT);

  hipMemsetAsync(hbuf, 0, 262144, stream);
  hipMemsetAsync(cnt, 0, 256, stream);

  k_len<<<1, 64, 0, stream>>>(mask, len);
  k_xconv<<<8192, 256, 0, stream>>>(x, xbf);
  k_wprep<<<4096, 256, 0, stream>>>(Wi_f, Wi_b, Wh_f, Wh_b, WiT, WhT);
  k_bias<<<32, 256, 0, stream>>>(b_f, b_b, bp);

  dim3 g(64, 64);
  k_gemm<<<g, 256, 0, stream>>>(xbf, WiT, bp, XG);

  k_recur<<<128, 512, 0, stream>>>(XG, WhT, len, hbuf, out, cnt);
}

// Round 4
// 1804.046 us; speedup vs baseline: 2.5182x; 1.0002x over previous
//
#include <hip/hip_runtime.h>
#include <hip/hip_bf16.h>
#include <stdint.h>

typedef __attribute__((ext_vector_type(4))) float f32x4;
typedef __attribute__((ext_vector_type(8))) short short8;
typedef __attribute__((ext_vector_type(4))) short short4v;

// ---------------- workspace layout (bytes) ----------------
#define OFF_XBF  ((size_t)0)            // [8192][1024] bf16 = 16777216
#define OFF_WIT  ((size_t)16777216)     // [2*4096][1024] bf16 = 16777216
#define OFF_WHT  ((size_t)33554432)     // [2*4096][1024] bf16 = 16777216
#define OFF_XG   ((size_t)50331648)     // [8192][8192] bf16 = 134217728
#define OFF_H    ((size_t)184549376)    // [2 parity][2 dir][32][1024] bf16 = 262144
#define OFF_BIAS ((size_t)184811520)    // [8192] f32 = 32768
#define OFF_LEN  ((size_t)184844288)    // [32] i32
#define OFF_CNT  ((size_t)184844416)    // flags: [2 dir][64] u32 = 512B

__device__ __forceinline__ short f2bf(float f) {
  union { float f; uint32_t u; } v; v.f = f;
  uint32_t u = v.u;
  uint32_t r = (u + 0x7fffu + ((u >> 16) & 1u)) >> 16;
  return (short)r;
}
__device__ __forceinline__ float bf2f(short s) {
  union { uint32_t u; float f; } v; v.u = ((uint32_t)(uint16_t)s) << 16;
  return v.f;
}

// ---------------- lengths ----------------
__global__ void k_len(const int* __restrict__ mask, int* __restrict__ len) {
  int b = threadIdx.x;
  if (b < 32) {
    int s = 0;
    for (int t = 0; t < 256; t++) s += mask[b * 256 + t];
    len[b] = s;
  }
}

// ---------------- x -> bf16, [B,T,D] -> [(t*32+b), D] ----------------
__global__ void k_xconv(const float* __restrict__ x, short* __restrict__ xbf) {
  int bid = blockIdx.x;              // 0..8191 = b*256 + t
  int b = bid >> 8, t = bid & 255;
  int d = threadIdx.x * 4;
  const float* sp = x + ((size_t)bid) * 1024 + d;
  float4 v = *(const float4*)sp;
  short4v o;
  o.x = f2bf(v.x); o.y = f2bf(v.y); o.z = f2bf(v.z); o.w = f2bf(v.w);
  *(short4v*)(xbf + ((size_t)(t * 32 + b)) * 1024 + d) = o;
}

// ------- weights: transpose [k][4096] f32 -> [n_perm][k] bf16, gate-interleaved perm -------
// perm: p = g4*16 + gate*4 + h4  <->  orig col c = gate*1024 + g4*4 + h4
__global__ void k_wprep(const float* __restrict__ Wi_f, const float* __restrict__ Wi_b,
                        const float* __restrict__ Wh_f, const float* __restrict__ Wh_b,
                        short* __restrict__ WiT, short* __restrict__ WhT) {
  __shared__ short ldsT[64 * 72];
  int id = blockIdx.x;               // 4096 blocks
  int which = id >> 11, dir = (id >> 10) & 1, tile = id & 1023;
  int kt = (tile >> 6) * 64, c0 = (tile & 63) * 64;
  const float* src = (which == 0) ? (dir == 0 ? Wi_f : Wi_b)
                                  : (dir == 0 ? Wh_f : Wh_b);
  short* dst = (which == 0) ? WiT : WhT;
  int tid = threadIdx.x;
#pragma unroll 4
  for (int i = 0; i < 16; i++) {
    int idx = i * 256 + tid;
    int kk = idx >> 6, cc = idx & 63;
    float v = src[(size_t)(kt + kk) * 4096 + c0 + cc];
    ldsT[cc * 72 + kk] = f2bf(v);    // transposed store
  }
  __syncthreads();
  int rowc = tid >> 2, part = tid & 3;
  int cg = c0 + rowc;
  int gate = cg >> 10, hc = cg & 1023;
  int p = (hc >> 2) * 16 + gate * 4 + (hc & 3);
  int n = dir * 4096 + p;
  short8 v0 = *(short8*)&ldsT[rowc * 72 + part * 16];
  short8 v1 = *(short8*)&ldsT[rowc * 72 + part * 16 + 8];
  *(short8*)(dst + (size_t)n * 1024 + kt + part * 16) = v0;
  *(short8*)(dst + (size_t)n * 1024 + kt + part * 16 + 8) = v1;
}

// ---------------- bias permute ----------------
__global__ void k_bias(const float* __restrict__ bf_, const float* __restrict__ bb_,
                       float* __restrict__ bp) {
  int n = blockIdx.x * 256 + threadIdx.x;   // 0..8191
  int dir = n >> 12, p = n & 4095;
  int gate = (p >> 2) & 3, g4 = p >> 4, h4 = p & 3;
  int c = gate * 1024 + g4 * 4 + h4;
  bp[n] = (dir == 0 ? bf_ : bb_)[c];
}

// ---------------- XG = xbf @ WiT^T + bias : [8192][8192] bf16 ----------------
__global__ void k_gemm(const short* __restrict__ Abf,   // xbf [8192][1024]
                       const short* __restrict__ Bbf,   // WiT [8192][1024]
                       const float* __restrict__ bias,  // [8192]
                       short* __restrict__ C) {         // XG [8192][8192]
  __shared__ char Ash[128 * 144];
  __shared__ char Bsh[128 * 144];
  const int tid = threadIdx.x;
  const int lane = tid & 63, wid = tid >> 6;
  const int wm = wid >> 1, wn = wid & 1;
  const int l15 = lane & 15, lg = lane >> 4;
  const int m0 = blockIdx.y * 128, n0 = blockIdx.x * 128;

  f32x4 acc[4][4];
#pragma unroll
  for (int i = 0; i < 4; i++)
#pragma unroll
    for (int j = 0; j < 4; j++) acc[i][j] = (f32x4){0.f, 0.f, 0.f, 0.f};

  for (int kt = 0; kt < 1024; kt += 64) {
#pragma unroll
    for (int i = 0; i < 4; i++) {
      int chunk = i * 256 + tid;          // 0..1023
      int row = chunk >> 3, kc = chunk & 7;
      *(short8*)(Ash + row * 144 + kc * 16) =
          *(const short8*)(Abf + (size_t)(m0 + row) * 1024 + kt + kc * 8);
      *(short8*)(Bsh + row * 144 + kc * 16) =
          *(const short8*)(Bbf + (size_t)(n0 + row) * 1024 + kt + kc * 8);
    }
    __syncthreads();
#pragma unroll
    for (int kk = 0; kk < 2; kk++) {
      short8 af[4], bfv[4];
#pragma unroll
      for (int mt = 0; mt < 4; mt++)
        af[mt] = *(const short8*)(Ash + (wm * 64 + mt * 16 + l15) * 144 + kk * 64 + lg * 16);
#pragma unroll
      for (int ntc = 0; ntc < 4; ntc++)
        bfv[ntc] = *(const short8*)(Bsh + (wn * 64 + ntc * 16 + l15) * 144 + kk * 64 + lg * 16);
#pragma unroll
      for (int mt = 0; mt < 4; mt++)
#pragma unroll
        for (int ntc = 0; ntc < 4; ntc++)
          acc[mt][ntc] = __builtin_amdgcn_mfma_f32_16x16x32_bf16(af[mt], bfv[ntc], acc[mt][ntc], 0, 0, 0);
    }
    __syncthreads();
  }
  float bs[4];
#pragma unroll
  for (int ntc = 0; ntc < 4; ntc++) bs[ntc] = bias[n0 + wn * 64 + ntc * 16 + l15];
#pragma unroll
  for (int mt = 0; mt < 4; mt++) {
    int row = m0 + wm * 64 + mt * 16 + lg * 4;
#pragma unroll
    for (int ntc = 0; ntc < 4; ntc++) {
      int col = n0 + wn * 64 + ntc * 16 + l15;
#pragma unroll
      for (int r = 0; r < 4; r++)
        C[(size_t)(row + r) * 8192 + col] = f2bf(acc[mt][ntc][r] + bs[ntc]);
    }
  }
}

// ---------------- persistent recurrence ----------------
// 128 blocks x 512 thr (8 waves). dir = bid>>6, nblk = bid&63 owns permuted
// z-cols [nblk*64, nblk*64+64) = h-cols [nblk*16, nblk*16+16).
// Wave (mt=wid>>2, nt=wid&3): 16 batches x 16 z-cols. Wh in 128 VGPRs/wave.
// Barrier: per-producer flag array (relaxed 4B store, no RMW) + wave0
// 64-lane coalesced poll + one acquire fence per block per step.
__global__ void __launch_bounds__(512, 1) k_recur(
    const short* __restrict__ XG,    // [8192][8192] bf16
    const short* __restrict__ WhT,   // [2*4096][1024] bf16
    const int* __restrict__ len,
    short* __restrict__ hbuf,        // [2][2][32][1024] bf16
    float* __restrict__ out,         // [32][256][2048] f32
    unsigned int* __restrict__ flags) {  // [2][64]
  __shared__ char Hld[65536];
  const int tid = threadIdx.x;
  const int lane = tid & 63;
  const int wid = tid >> 6;
  const int bidx = blockIdx.x;
  const int dir = bidx >> 6;
  const int nblk = bidx & 63;
  const int mt = wid >> 2, nt = wid & 3;
  const int l15 = lane & 15, lg = lane >> 4;

  // B-fragments (Wh columns), resident in registers for all 256 steps
  const int ncol = dir * 4096 + nblk * 64 + nt * 16 + l15;
  const short* wrow = WhT + (size_t)ncol * 1024;
  short8 bfr[32];
#pragma unroll
  for (int kk = 0; kk < 32; kk++)
    bfr[kk] = *(const short8*)(wrow + kk * 32 + lg * 8);

  float c_reg[4] = {0.f, 0.f, 0.f, 0.f};
  int lenv[4];
#pragma unroll
  for (int r = 0; r < 4; r++) lenv[r] = len[mt * 16 + lg * 4 + r];

  const int c4 = l15;
  const int gate = c4 >> 2;
  const int brow = mt * 16 + l15;
  const int sw = (brow & 7) << 4;
  const int abase = brow * 2048 + (lg << 4);
  const int hcol0 = nblk * 16 + nt * 4;    // first h-col of this wave's tile

  // prefetch XG for t=0
  float xg_pf[4];
#pragma unroll
  for (int r = 0; r < 4; r++) {
    int b_r = mt * 16 + lg * 4 + r;
    int tt = (dir == 0) ? 0 : ((lenv[r] - 1) & 255);
    xg_pf[r] = bf2f(XG[(size_t)(tt * 32 + b_r) * 8192 + ncol]);
  }

  for (int t = 0; t < 256; t++) {
    // stage h (read parity t&1) into LDS with XOR swizzle (normal cached loads)
    const short* hsrc = hbuf + (size_t)(((t & 1) * 2 + dir) * 32768);
#pragma unroll
    for (int i = 0; i < 8; i++) {
      int chunk = i * 512 + tid;       // 0..4095, 16B each
      int row = chunk >> 7;
      short8 v = *(const short8*)(hsrc + chunk * 8);
      int dst = (chunk * 16) ^ ((row & 7) << 4);
      *(short8*)(Hld + dst) = v;
    }
    __syncthreads();

    // two independent MFMA chains to halve dependent latency
    f32x4 accA = (f32x4){0.f, 0.f, 0.f, 0.f};
    f32x4 accB = (f32x4){0.f, 0.f, 0.f, 0.f};
#pragma unroll
    for (int kk = 0; kk < 16; kk++) {
      short8 afA = *(const short8*)(Hld + ((abase + kk * 64) ^ sw));
      short8 afB = *(const short8*)(Hld + ((abase + (kk + 16) * 64) ^ sw));
      accA = __builtin_amdgcn_mfma_f32_16x16x32_bf16(afA, bfr[kk], accA, 0, 0, 0);
      accB = __builtin_amdgcn_mfma_f32_16x16x32_bf16(afB, bfr[kk + 16], accB, 0, 0, 0);
    }

    f32x4 hsave[4];
#pragma unroll
    for (int r = 0; r < 4; r++) {
      int b_r = mt * 16 + lg * 4 + r;
      float z = accA[r] + accB[r] + xg_pf[r];
      float s = (gate == 2) ? tanhf(z) : 1.f / (1.f + expf(-z));
      float x8 = __shfl_xor(s, 8);     // i<->g, f<->o
      float pI = s * x8;               // on i-lanes: sig(i)*tanh(g)
      float v = (gate == 0) ? pI : s;
      float x4 = __shfl_xor(v, 4);     // i-lane receives sig(f)
      float o4 = __shfl_xor(x8, 4);    // i-lane receives sig(o)
      float cn = fmaf(x4, c_reg[r], pI);
      float h = o4 * tanhf(cn);
      if (c4 < 4) c_reg[r] = cn;
      // pack 4 cols (lanes c4=0..3) into 8B, publish via relaxed agent atomic
      uint32_t hb = (uint32_t)(uint16_t)f2bf(h);
      uint32_t p0 = hb | (__shfl_xor(hb, 1) << 16);
      uint32_t q  = __shfl_xor(p0, 2);
      if (c4 == 0) {
        unsigned long long p = (unsigned long long)p0 | ((unsigned long long)q << 32);
        unsigned long long* haddr = (unsigned long long*)
          (hbuf + (size_t)((((t + 1) & 1) * 2 + dir) * 32768) + b_r * 1024 + hcol0);
        __hip_atomic_store(haddr, p, __ATOMIC_RELAXED, __HIP_MEMORY_SCOPE_AGENT);
        hsave[r].x = bf2f((short)(p0 & 0xffff));
        hsave[r].y = bf2f((short)(p0 >> 16));
        hsave[r].z = bf2f((short)(q & 0xffff));
        hsave[r].w = bf2f((short)(q >> 16));
      }
    }

    // arrive: drain h stores (per-wave vmcnt before s_barrier), then one flag store
    __syncthreads();
    if (tid == 0) {
      __hip_atomic_store(flags + dir * 64 + nblk, (unsigned int)(t + 1),
                         __ATOMIC_RELAXED, __HIP_MEMORY_SCOPE_AGENT);
    }
    __builtin_amdgcn_sched_barrier(0);   // keep flag store ahead of the code below

    // deferred work overlapping the spin: out stores (float4) + XG prefetch t+1
    if (c4 == 0) {
#pragma unroll
      for (int r = 0; r < 4; r++) {
        int b_r = mt * 16 + lg * 4 + r;
        int tt = (dir == 0) ? t : ((lenv[r] - 1 - t) & 255);
        *(f32x4*)(out + ((size_t)b_r * 256 + tt) * 2048 + dir * 1024 + hcol0) = hsave[r];
      }
    }
    int tn = (t < 255) ? t + 1 : 255;
#pragma unroll
    for (int r = 0; r < 4; r++) {
      int b_r = mt * 16 + lg * 4 + r;
      int tt = (dir == 0) ? tn : ((lenv[r] - 1 - tn) & 255);
      xg_pf[r] = bf2f(XG[(size_t)(tt * 32 + b_r) * 8192 + ncol]);
    }

    // wait: wave0 polls all 64 producer flags with one coalesced load
    if (wid == 0) {
      unsigned int* fl = flags + dir * 64 + lane;
      unsigned int tgt = (unsigned int)(t + 1);
      for (;;) {
        unsigned int v = __hip_atomic_load(fl, __ATOMIC_RELAXED, __HIP_MEMORY_SCOPE_AGENT);
        if (__all((int)(v >= tgt))) break;
        __builtin_amdgcn_s_sleep(1);
      }
      __builtin_amdgcn_fence(__ATOMIC_ACQUIRE, "agent");  // one buffer_inv
    }
    __syncthreads();
  }
}

extern "C" void kernel_launch(void* const* d_in, const int* in_sizes, int n_in,
                              void* d_out, int out_size, void* d_ws, size_t ws_size,
                              hipStream_t stream) {
  const float* x    = (const float*)d_in[0];
  const int*   mask = (const int*)d_in[1];
  const float* Wi_f = (const float*)d_in[2];
  const float* Wh_f = (const float*)d_in[3];
  const float* b_f  = (const float*)d_in[4];
  const float* Wi_b = (const float*)d_in[5];
  const float* Wh_b = (const float*)d_in[6];
  const float* b_b  = (const float*)d_in[7];
  float* out = (float*)d_out;
  char* ws = (char*)d_ws;

  short* xbf  = (short*)(ws + OFF_XBF);
  short* WiT  = (short*)(ws + OFF_WIT);
  short* WhT  = (short*)(ws + OFF_WHT);
  short* XG   = (short*)(ws + OFF_XG);
  short* hbuf = (short*)(ws + OFF_H);
  float* bp   = (float*)(ws + OFF_BIAS);
  int*   len  = (int*)(ws + OFF_LEN);
  unsigned int* flags = (unsigned int*)(ws + OFF_CNT);

  hipMemsetAsync(hbuf, 0, 262144, stream);
  hipMemsetAsync(flags, 0, 512, stream);

  k_len<<<1, 64, 0, stream>>>(mask, len);
  k_xconv<<<8192, 256, 0, stream>>>(x, xbf);
  k_wprep<<<4096, 256, 0, stream>>>(Wi_f, Wi_b, Wh_f, Wh_b, WiT, WhT);
  k_bias<<<32, 256, 0, stream>>>(b_f, b_b, bp);

  dim3 g(64, 64);
  k_gemm<<<g, 256, 0, stream>>>(xbf, WiT, bp, XG);

  k_recur<<<128, 512, 0, stream>>>(XG, WhT, len, hbuf, out, flags);
}